// Round 11
// baseline (148.669 us; speedup 1.0000x reference)
//
#include <hip/hip_runtime.h>

// ---------------------------------------------------------------------------
// FiLM-conditioned attention block, bf16 MFMA implementation. Round 11
// (= Round 10 resubmitted after container-level infra failure):
// attn: LDS-staged K/V (coalesced global->LDS, padded conflict-free ds_read)
// shared by 4 waves x 64q = 256q/block; 8-way K-split across blocks with
// global partial merge kernel. V stored in 2KB key-tiles.
// Shapes: b=2, c=256, n=4096, 4 heads x 32d.
// ---------------------------------------------------------------------------

typedef __bf16 bf16x8 __attribute__((ext_vector_type(8)));
typedef float  f32x16 __attribute__((ext_vector_type(16)));
typedef unsigned uint2v __attribute__((ext_vector_type(2)));

#define MFMA(a, b, c) __builtin_amdgcn_mfma_f32_32x32x16_bf16((a), (b), (c), 0, 0, 0)
#define PLSWAP(a, b) __builtin_amdgcn_permlane32_swap((a), (b), false, false)

static constexpr float kLOG2E = 1.4426950408889634f;
static constexpr float kSCALE = 0.17677669529663687f; // 32^-0.5

__device__ __forceinline__ unsigned short bf16r(float x) {
  union { float f; unsigned u; } v; v.f = x;
  return (unsigned short)((v.u + 0x7FFFu + ((v.u >> 16) & 1u)) >> 16); // RTNE
}
__device__ __forceinline__ float fast_silu(float x) {
  return x / (1.0f + __builtin_amdgcn_exp2f(-x * kLOG2E));
}
__device__ __forceinline__ f32x16 zero16() {
  f32x16 z;
#pragma unroll
  for (int i = 0; i < 16; ++i) z[i] = 0.0f;
  return z;
}
__device__ __forceinline__ bf16x8 ld_frag(const unsigned short* p) {
  return *reinterpret_cast<const bf16x8*>(p);
}
__device__ __forceinline__ bf16x8 ld_lds_frag(const unsigned short* p) {
  union { unsigned long long q[2]; bf16x8 v; } u;   // 2x ds_read_b64 (8B-aligned)
  u.q[0] = *(const unsigned long long*)(p);
  u.q[1] = *(const unsigned long long*)(p + 4);
  return u.v;
}

// ---------------------------------------------------------------------------
// prep: blocks 0..31 = film1 (8-way K-split GEMV), blocks 32..543 = xpose.
// ---------------------------------------------------------------------------
__global__ __launch_bounds__(256) void prep(const float* __restrict__ x,
                                            unsigned short* __restrict__ xT,
                                            const float* __restrict__ te,
                                            const float* __restrict__ w_mlp,
                                            const float* __restrict__ b_mlp,
                                            float* __restrict__ fparams) {
  __shared__ unsigned short lds[64][66];
  int bid = blockIdx.x;
  if (bid < 32) {
    int g = bid * 256 + threadIdx.x;   // 0..8191
    int pair = g >> 3, ks = g & 7;
    int b = pair >> 9, o = pair & 511;
    const float4* w4 = (const float4*)(w_mlp + (size_t)o * 512 + ks * 64);
    const float4* t4 = (const float4*)(te + (size_t)b * 512 + ks * 64);
    float s = 0.0f;
#pragma unroll 4
    for (int k = 0; k < 16; ++k) {
      float4 wv = w4[k];
      float4 tv = t4[k];
      s += wv.x * fast_silu(tv.x) + wv.y * fast_silu(tv.y) +
           wv.z * fast_silu(tv.z) + wv.w * fast_silu(tv.w);
    }
    s += __shfl_xor(s, 1, 64);
    s += __shfl_xor(s, 2, 64);
    s += __shfl_xor(s, 4, 64);
    if (ks == 0) {
      float t_val = s + b_mlp[o];
      fparams[b * 512 + o] = (o < 256) ? (t_val + 1.0f) : t_val;
    }
    return;
  }
  int bid2 = bid - 32;                // (b*4 + cblk)*64 + pblk
  int p0 = (bid2 & 63) * 64;
  int c0 = ((bid2 >> 6) & 3) * 64;
  int b  = bid2 >> 8;
  int t = threadIdx.x;
  int pl = t & 63, cw = t >> 6;
  const float* xb = x + ((size_t)b * 256 + c0) * 4096 + p0;
#pragma unroll
  for (int r = 0; r < 16; ++r) {
    int cl = cw + r * 4;
    lds[pl][cl] = bf16r(xb[(size_t)cl * 4096 + pl]);
  }
  __syncthreads();
  unsigned short* out = xT + ((size_t)b * 4096 + p0) * 256 + c0;
#pragma unroll
  for (int rep = 0; rep < 2; ++rep) {
    int ch = t + rep * 256;
    int pr = ch >> 3, cc = (ch & 7) * 8;
    union { unsigned short u[8]; uint4 v; } pk;
#pragma unroll
    for (int i = 0; i < 8; ++i) pk.u[i] = lds[pr][cc + i];
    *(uint4*)(out + (size_t)pr * 256 + cc) = pk.v;
  }
}

// ---------------------------------------------------------------------------
// film2: Aeff[b][o][c] = bf16(w_qkv[o][c] * (scale+1)[b][c]) (Q rows pre-scaled
//        by SCALE*log2e), qb[b][o] = sum_c w_qkv[o][c]*shift[b][c] (same scale),
//        plus bf16 copy of w_out.  32-way c-split; 25088 threads (98 blocks).
// ---------------------------------------------------------------------------
__global__ __launch_bounds__(256) void film2(const float* __restrict__ w_qkv,
                                             const float* __restrict__ fparams,
                                             const float* __restrict__ w_out,
                                             unsigned short* __restrict__ Aeff,
                                             float* __restrict__ qb,
                                             unsigned short* __restrict__ WoBf) {
  int tid = blockIdx.x * 256 + threadIdx.x;   // 0..25087
  if (tid < 24576) {
    int row = tid >> 5, cs = tid & 31;        // 768 rows x 32-way c-split
    int b = row / 384, o = row % 384;
    float qs = (o < 128) ? (kSCALE * kLOG2E) : 1.0f;  // fold softmax exp2 scale into Q
    const float4* wr  = (const float4*)(w_qkv + (size_t)o * 256);
    const float4* sc4 = (const float4*)(fparams + b * 512);
    const float4* sh4 = (const float4*)(fparams + b * 512 + 256);
    unsigned short* arow = Aeff + ((size_t)b * 384 + o) * 256;
    float acc = 0.0f;
#pragma unroll
    for (int j = 0; j < 2; ++j) {
      int c4 = cs * 2 + j;
      float4 wv = wr[c4], scv = sc4[c4], shv = sh4[c4];
      acc += wv.x * shv.x + wv.y * shv.y + wv.z * shv.z + wv.w * shv.w;
      union { unsigned short u[4]; unsigned long long q; } pk;
      pk.u[0] = bf16r(wv.x * scv.x * qs);
      pk.u[1] = bf16r(wv.y * scv.y * qs);
      pk.u[2] = bf16r(wv.z * scv.z * qs);
      pk.u[3] = bf16r(wv.w * scv.w * qs);
      *(unsigned long long*)(arow + c4 * 4) = pk.q;
    }
    acc += __shfl_xor(acc, 1, 64);
    acc += __shfl_xor(acc, 2, 64);
    acc += __shfl_xor(acc, 4, 64);
    acc += __shfl_xor(acc, 8, 64);
    acc += __shfl_xor(acc, 16, 64);
    if (cs == 0) qb[b * 384 + o] = acc * qs;
  } else {
    int t = tid - 24576;   // 512 chunks x 64 elems of w_out (256x128)
    const float4* src = (const float4*)(w_out + (size_t)t * 64);
    unsigned short* dst = WoBf + (size_t)t * 64;
#pragma unroll 4
    for (int i = 0; i < 16; ++i) {
      float4 v = src[i];
      union { unsigned short u[4]; unsigned long long q; } pk;
      pk.u[0] = bf16r(v.x); pk.u[1] = bf16r(v.y);
      pk.u[2] = bf16r(v.z); pk.u[3] = bf16r(v.w);
      *(unsigned long long*)(dst + i * 4) = pk.q;
    }
  }
}

// ---------------------------------------------------------------------------
// qkv_gemm: C[o][p] = Aeff[b] @ xT[b]^T + qb.  M=384,N=4096,K=256 per batch.
// One wave per block computes a 32o x 32p tile (3072 waves = 3/SIMD).
// V stored TILED: Vt[bh][p>>5][d][p&31]  (2KB contiguous per 32-key tile,
// coalesced stores here and coalesced tile staging in attn).
// ---------------------------------------------------------------------------
__global__ __launch_bounds__(64) void qkv_gemm(const unsigned short* __restrict__ Aeff,
                                               const float* __restrict__ qb,
                                               const unsigned short* __restrict__ xT,
                                               unsigned short* __restrict__ Qb,
                                               unsigned short* __restrict__ Kb,
                                               unsigned short* __restrict__ Vt) {
  int bid = blockIdx.x;               // 3072: o_blk fastest (share B tile in L2)
  int o_blk = bid % 12;
  int rest = bid / 12;
  int b = rest & 1, p_blk = rest >> 1;
  int l = threadIdx.x, col = l & 31, hi = l >> 5;

  const unsigned short* Ab = Aeff + ((size_t)b * 384 + o_blk * 32) * 256;
  const unsigned short* Bb = xT + ((size_t)b * 4096 + p_blk * 32) * 256;

  f32x16 acc = zero16();
#pragma unroll
  for (int kc = 0; kc < 256; kc += 16) {
    bf16x8 a0 = ld_frag(Ab + (size_t)col * 256 + kc + hi * 8);
    bf16x8 b0 = ld_frag(Bb + (size_t)col * 256 + kc + hi * 8);
    acc = MFMA(a0, b0, acc);
  }

  int obase = o_blk * 32;                  // 32-aligned: one section+head per tile
  int sec = obase >> 7;                    // 0=Q 1=K 2=V
  int head = (obase & 127) >> 5;
  size_t bh = (size_t)b * 4 + head;
  int p = p_blk * 32 + col;
  if (sec < 2) {
    unsigned short* dst = (sec == 0 ? Qb : Kb) + (bh * 4096 + p) * 32;
#pragma unroll
    for (int g = 0; g < 4; ++g) {
      int dbase = 8 * g + 4 * hi;          // D-row = (reg&3)+8*(reg>>2)+4*hi
      union { unsigned short u[4]; unsigned long long q; } pk;
#pragma unroll
      for (int r = 0; r < 4; ++r)
        pk.u[r] = bf16r(acc[4 * g + r] + qb[b * 384 + obase + dbase + r]);
      *(unsigned long long*)(dst + dbase) = pk.q;
    }
  } else {
    // tiled V: offset = bh*131072 + (p>>5)*1024 + d*32 + (p&31); p>>5 == p_blk
    unsigned short* dst = Vt + bh * 131072 + (size_t)p_blk * 1024;
#pragma unroll
    for (int reg = 0; reg < 16; ++reg) {
      int d = (reg & 3) + 8 * (reg >> 2) + 4 * hi;
      dst[d * 32 + col] = bf16r(acc[reg] + qb[b * 384 + obase + d]);
    }
  }
}

// ---------------------------------------------------------------------------
// attn: no-max flash attention (range-safe), swapped QK^T.  Block = 4 waves x
// 64q = 256 q rows sharing K/V; keys [ks*512,(ks+1)*512) (16 tiles of 32).
// Per tile: 256 threads stage K(2KB)+V(2KB) coalesced into padded LDS
// (double-buffered), all waves ds_read frags (2-way conflicts only = free).
// Un-normalized partials (O, lsum) written to ws; attn_merge reduces 8 ks.
// ---------------------------------------------------------------------------
__device__ __forceinline__ void softmax_pv(f32x16 S, bf16x8 va0, bf16x8 va1,
                                           f32x16& O, float& lsum) {
#pragma unroll
  for (int i = 0; i < 16; ++i) S[i] = __builtin_amdgcn_exp2f(S[i]);
  float s0 = (S[0] + S[1]) + (S[2] + S[3]);
  float s1 = (S[4] + S[5]) + (S[6] + S[7]);
  float s2 = (S[8] + S[9]) + (S[10] + S[11]);
  float s3 = (S[12] + S[13]) + (S[14] + S[15]);
  lsum += (s0 + s1) + (s2 + s3);
  // P (D-layout: key=(reg&3)+8*(reg>>2)+4*hi) -> PV B-frags via permlane swaps
  union { __bf16 h[16]; unsigned u[8]; } pu;
#pragma unroll
  for (int i = 0; i < 16; ++i) pu.h[i] = (__bf16)S[i];   // v_cvt_pk_bf16_f32 pairs
  uint2v r0 = PLSWAP(pu.u[0], pu.u[2]);
  uint2v r1 = PLSWAP(pu.u[1], pu.u[3]);
  uint2v r2 = PLSWAP(pu.u[4], pu.u[6]);
  uint2v r3 = PLSWAP(pu.u[5], pu.u[7]);
  union { unsigned u[4]; bf16x8 v; } B0, B1;
  B0.u[0] = r0[0]; B0.u[1] = r1[0]; B0.u[2] = r0[1]; B0.u[3] = r1[1]; // keys 0..15
  B1.u[0] = r2[0]; B1.u[1] = r3[0]; B1.u[2] = r2[1]; B1.u[3] = r3[1]; // keys 16..31
  O = MFMA(va0, B0.v, O);            // O^T[d][q] accumulate
  O = MFMA(va1, B1.v, O);
}

__global__ __launch_bounds__(256, 4) void attn(const unsigned short* __restrict__ Qb,
                                               const unsigned short* __restrict__ Kb,
                                               const unsigned short* __restrict__ Vt,
                                               float* __restrict__ Opart,
                                               float* __restrict__ Lpart) {
  __shared__ unsigned short kv[2][2][32][36];   // [buf][K/V][row][32+4 pad] 9.2KB

  int bid = blockIdx.x;               // (bh*8 + ks)*16 + qblk
  int qblk = bid & 15;
  int ks   = (bid >> 4) & 7;
  int bh   = bid >> 7;
  int t = threadIdx.x;
  int w = t >> 6, l = t & 63, col = l & 31, hi = l >> 5;

  int q0 = qblk * 256 + w * 64;
  const unsigned short* Qp = Qb + ((size_t)bh * 4096 + q0) * 32;
  bf16x8 qf0 = ld_frag(Qp + col * 32 + hi * 8);              // q half A: d 0..15
  bf16x8 qf1 = ld_frag(Qp + col * 32 + 16 + hi * 8);         //           d 16..31
  bf16x8 qg0 = ld_frag(Qp + (col + 32) * 32 + hi * 8);       // q half B
  bf16x8 qg1 = ld_frag(Qp + (col + 32) * 32 + 16 + hi * 8);

  // staging role: thread t stages 16B: sec 0=K 1=V, row rr, 16B-chunk cc
  int sec = t >> 7, rr = (t & 127) >> 2, cc = t & 3;
  const unsigned short* gsrc =
      (sec ? Vt : Kb) + (size_t)bh * 131072 + ks * 16384 + (t & 127) * 8;

  const f32x16 zc = zero16();
  f32x16 Oa = zero16(), Obb = zero16();
  float lsuma = 0.0f, lsumb = 0.0f;

  uint4 greg = *(const uint4*)(gsrc);            // tile 0

  for (int tt = 0; tt < 16; ++tt) {
    __syncthreads();                             // buf consumers (tt-2) done
    int buf = tt & 1;
    unsigned short* d0 = &kv[buf][sec][rr][cc * 8];
    *(unsigned long long*)(d0)     = ((const unsigned long long*)&greg)[0];
    *(unsigned long long*)(d0 + 4) = ((const unsigned long long*)&greg)[1];
    if (tt < 15) greg = *(const uint4*)(gsrc + (tt + 1) * 1024);  // prefetch
    __syncthreads();                             // tile tt visible

    bf16x8 ka0 = ld_lds_frag(&kv[buf][0][col][hi * 8]);
    bf16x8 ka1 = ld_lds_frag(&kv[buf][0][col][16 + hi * 8]);
    bf16x8 va0 = ld_lds_frag(&kv[buf][1][col][hi * 8]);
    bf16x8 va1 = ld_lds_frag(&kv[buf][1][col][16 + hi * 8]);

    f32x16 Sa = MFMA(ka0, qf0, zc);
    Sa = MFMA(ka1, qf1, Sa);
    softmax_pv(Sa, va0, va1, Oa, lsuma);

    f32x16 Sb = MFMA(ka0, qg0, zc);
    Sb = MFMA(ka1, qg1, Sb);
    softmax_pv(Sb, va0, va1, Obb, lsumb);
  }

  uint2v lra = PLSWAP(__float_as_uint(lsuma), __float_as_uint(lsuma));
  uint2v lrb = PLSWAP(__float_as_uint(lsumb), __float_as_uint(lsumb));
  float lta = __uint_as_float(lra[0]) + __uint_as_float(lra[1]);
  float ltb = __uint_as_float(lrb[0]) + __uint_as_float(lrb[1]);

  // ---- write un-normalized partials: Opart[(bh*8+ks)][d][4096q] fp32 ----
  float* op = Opart + (size_t)(bh * 8 + ks) * 131072;
  float* lp = Lpart + (size_t)(bh * 8 + ks) * 4096;
#pragma unroll
  for (int r = 0; r < 16; ++r) {
    int d = (r & 3) + 8 * (r >> 2) + 4 * hi;
    op[d * 4096 + q0 + col]      = Oa[r];
    op[d * 4096 + q0 + 32 + col] = Obb[r];
  }
  if (hi == 0) {
    lp[q0 + col]      = lta;
    lp[q0 + 32 + col] = ltb;
  }
}

// ---------------------------------------------------------------------------
// attn_merge: Ob[bh][q][d] = (sum_ks Opart[bh,ks][d][q]) / (sum_ks Lpart).
// One thread per (bh, q, d-pair); 2048 blocks x 256.
// ---------------------------------------------------------------------------
__global__ __launch_bounds__(256) void attn_merge(const float* __restrict__ Opart,
                                                  const float* __restrict__ Lpart,
                                                  unsigned short* __restrict__ Ob) {
  int idx = blockIdx.x * 256 + threadIdx.x;   // 524288
  int dp = idx & 15;
  int q  = (idx >> 4) & 4095;
  int bh = idx >> 16;
  float s0 = 0.0f, s1 = 0.0f, L = 0.0f;
#pragma unroll
  for (int ks = 0; ks < 8; ++ks) {
    const float* op = Opart + (size_t)(bh * 8 + ks) * 131072;
    s0 += op[(2 * dp) * 4096 + q];
    s1 += op[(2 * dp + 1) * 4096 + q];
    L  += Lpart[(size_t)(bh * 8 + ks) * 4096 + q];
  }
  float inv = 1.0f / L;
  union { unsigned short u[2]; unsigned v; } pk;
  pk.u[0] = bf16r(s0 * inv);
  pk.u[1] = bf16r(s1 * inv);
  *(unsigned*)(Ob + ((size_t)bh * 4096 + q) * 32 + 2 * dp) = pk.v;
}

// ---------------------------------------------------------------------------
// out_gemm: out[b][o][p] = w_out[o][:] @ O[b][:][p] + b_out[o].
// M=256, N=4096, K=128.  One wave per block, 32o x 32p (2048 waves = 2/SIMD).
// ---------------------------------------------------------------------------
__global__ __launch_bounds__(64) void out_gemm(const unsigned short* __restrict__ Wo,
                                               const unsigned short* __restrict__ Ob,
                                               const float* __restrict__ b_out,
                                               float* __restrict__ out) {
  int bid = blockIdx.x;               // 2048: o_blk fastest
  int o_blk = bid & 7;
  int rest = bid >> 3;
  int b = rest & 1, p_blk = rest >> 1;
  int l = threadIdx.x, col = l & 31, hi = l >> 5;

  const unsigned short* Ab = Wo + (size_t)(o_blk * 32) * 128;
  f32x16 acc = zero16();
#pragma unroll
  for (int kc = 0; kc < 128; kc += 16) {
    int head = kc >> 5;
    int doff = (kc & 16) + hi * 8;
    const unsigned short* Bb =
        Ob + (((size_t)b * 4 + head) * 4096 + p_blk * 32) * 32 + doff;
    bf16x8 a0 = ld_frag(Ab + (size_t)col * 128 + kc + hi * 8);
    bf16x8 b0 = ld_frag(Bb + (size_t)col * 32);
    acc = MFMA(a0, b0, acc);
  }
  int p = p_blk * 32 + col;
#pragma unroll
  for (int reg = 0; reg < 16; ++reg) {
    int o = o_blk * 32 + (reg & 3) + 8 * (reg >> 2) + 4 * hi;
    out[((size_t)b * 256 + o) * 4096 + p] = acc[reg] + b_out[o];
  }
}

// ---------------------------------------------------------------------------
extern "C" void kernel_launch(void* const* d_in, const int* in_sizes, int n_in,
                              void* d_out, int out_size, void* d_ws, size_t ws_size,
                              hipStream_t stream) {
  const float* x     = (const float*)d_in[0];
  const float* te    = (const float*)d_in[1];
  const float* w_mlp = (const float*)d_in[2];
  const float* b_mlp = (const float*)d_in[3];
  const float* w_qkv = (const float*)d_in[4];
  const float* w_out = (const float*)d_in[5];
  const float* b_out = (const float*)d_in[6];

  char* ws = (char*)d_ws;
  float*          fparams = (float*)(ws + 0);                 //   4 KB
  float*          qb      = (float*)(ws + 4096);              //   3 KB
  unsigned short* Aeff    = (unsigned short*)(ws + 8192);     // 384 KB
  unsigned short* WoBf    = (unsigned short*)(ws + 401408);   //  64 KB
  unsigned short* xT      = (unsigned short*)(ws + 466944);   //   4 MB
  unsigned short* Qb      = (unsigned short*)(ws + 4661248);  //   2 MB
  unsigned short* Kb      = (unsigned short*)(ws + 6758400);  //   2 MB
  unsigned short* Vt      = (unsigned short*)(ws + 8855552);  //   2 MB
  unsigned short* Ob      = (unsigned short*)(ws + 10952704); //   2 MB
  float*          Opart   = (float*)(ws + 13049856);          //  32 MB
  float*          Lpart   = (float*)(ws + 46604288);          //   1 MB -> 47.7 MB
  float* out = (float*)d_out;

  hipLaunchKernelGGL(prep, dim3(544), dim3(256), 0, stream, x, xT, te, w_mlp,
                     b_mlp, fparams);
  hipLaunchKernelGGL(film2, dim3(98), dim3(256), 0, stream, w_qkv, fparams, w_out,
                     Aeff, qb, WoBf);
  hipLaunchKernelGGL(qkv_gemm, dim3(3072), dim3(64), 0, stream, Aeff, qb, xT, Qb, Kb, Vt);
  hipLaunchKernelGGL(attn, dim3(1024), dim3(256), 0, stream, Qb, Kb, Vt, Opart, Lpart);
  hipLaunchKernelGGL(attn_merge, dim3(2048), dim3(256), 0, stream, Opart, Lpart, Ob);
  hipLaunchKernelGGL(out_gemm, dim3(2048), dim3(64), 0, stream, WoBf, Ob, b_out, out);
}

// Round 12
// 133.022 us; speedup vs baseline: 1.1176x; 1.1176x over previous
//
#include <hip/hip_runtime.h>

// ---------------------------------------------------------------------------
// FiLM-conditioned attention block, bf16 MFMA implementation. Round 12:
// coalescing everywhere: LDS-staged 64x64 GEMM tiles (XOR-swizzled),
// conflict-free chunk-major attn K/V LDS, coalesced attn_merge.
// Shapes: b=2, c=256, n=4096, 4 heads x 32d.
// ---------------------------------------------------------------------------

typedef __bf16 bf16x8 __attribute__((ext_vector_type(8)));
typedef float  f32x16 __attribute__((ext_vector_type(16)));
typedef unsigned uint2v __attribute__((ext_vector_type(2)));

#define MFMA(a, b, c) __builtin_amdgcn_mfma_f32_32x32x16_bf16((a), (b), (c), 0, 0, 0)
#define PLSWAP(a, b) __builtin_amdgcn_permlane32_swap((a), (b), false, false)

static constexpr float kLOG2E = 1.4426950408889634f;
static constexpr float kSCALE = 0.17677669529663687f; // 32^-0.5

__device__ __forceinline__ unsigned short bf16r(float x) {
  union { float f; unsigned u; } v; v.f = x;
  return (unsigned short)((v.u + 0x7FFFu + ((v.u >> 16) & 1u)) >> 16); // RTNE
}
__device__ __forceinline__ float fast_silu(float x) {
  return x / (1.0f + __builtin_amdgcn_exp2f(-x * kLOG2E));
}
__device__ __forceinline__ f32x16 zero16() {
  f32x16 z;
#pragma unroll
  for (int i = 0; i < 16; ++i) z[i] = 0.0f;
  return z;
}
__device__ __forceinline__ bf16x8 ld_frag(const unsigned short* p) {
  return *reinterpret_cast<const bf16x8*>(p);
}

// ---------------------------------------------------------------------------
// prep: blocks 0..31 = film1 (8-way K-split GEMV), blocks 32..543 = xpose.
// ---------------------------------------------------------------------------
__global__ __launch_bounds__(256) void prep(const float* __restrict__ x,
                                            unsigned short* __restrict__ xT,
                                            const float* __restrict__ te,
                                            const float* __restrict__ w_mlp,
                                            const float* __restrict__ b_mlp,
                                            float* __restrict__ fparams) {
  __shared__ unsigned short lds[64][66];
  int bid = blockIdx.x;
  if (bid < 32) {
    int g = bid * 256 + threadIdx.x;   // 0..8191
    int pair = g >> 3, ks = g & 7;
    int b = pair >> 9, o = pair & 511;
    const float4* w4 = (const float4*)(w_mlp + (size_t)o * 512 + ks * 64);
    const float4* t4 = (const float4*)(te + (size_t)b * 512 + ks * 64);
    float s = 0.0f;
#pragma unroll 4
    for (int k = 0; k < 16; ++k) {
      float4 wv = w4[k];
      float4 tv = t4[k];
      s += wv.x * fast_silu(tv.x) + wv.y * fast_silu(tv.y) +
           wv.z * fast_silu(tv.z) + wv.w * fast_silu(tv.w);
    }
    s += __shfl_xor(s, 1, 64);
    s += __shfl_xor(s, 2, 64);
    s += __shfl_xor(s, 4, 64);
    if (ks == 0) {
      float t_val = s + b_mlp[o];
      fparams[b * 512 + o] = (o < 256) ? (t_val + 1.0f) : t_val;
    }
    return;
  }
  int bid2 = bid - 32;                // (b*4 + cblk)*64 + pblk
  int p0 = (bid2 & 63) * 64;
  int c0 = ((bid2 >> 6) & 3) * 64;
  int b  = bid2 >> 8;
  int t = threadIdx.x;
  int pl = t & 63, cw = t >> 6;
  const float* xb = x + ((size_t)b * 256 + c0) * 4096 + p0;
#pragma unroll
  for (int r = 0; r < 16; ++r) {
    int cl = cw + r * 4;
    lds[pl][cl] = bf16r(xb[(size_t)cl * 4096 + pl]);
  }
  __syncthreads();
  unsigned short* out = xT + ((size_t)b * 4096 + p0) * 256 + c0;
#pragma unroll
  for (int rep = 0; rep < 2; ++rep) {
    int ch = t + rep * 256;
    int pr = ch >> 3, cc = (ch & 7) * 8;
    union { unsigned short u[8]; uint4 v; } pk;
#pragma unroll
    for (int i = 0; i < 8; ++i) pk.u[i] = lds[pr][cc + i];
    *(uint4*)(out + (size_t)pr * 256 + cc) = pk.v;
  }
}

// ---------------------------------------------------------------------------
// film2: Aeff[b][o][c] = bf16(w_qkv[o][c] * (scale+1)[b][c]) (Q rows pre-scaled
//        by SCALE*log2e), qb[b][o] = sum_c w_qkv[o][c]*shift[b][c] (same scale),
//        plus bf16 copy of w_out.  32-way c-split; 25088 threads (98 blocks).
// ---------------------------------------------------------------------------
__global__ __launch_bounds__(256) void film2(const float* __restrict__ w_qkv,
                                             const float* __restrict__ fparams,
                                             const float* __restrict__ w_out,
                                             unsigned short* __restrict__ Aeff,
                                             float* __restrict__ qb,
                                             unsigned short* __restrict__ WoBf) {
  int tid = blockIdx.x * 256 + threadIdx.x;   // 0..25087
  if (tid < 24576) {
    int row = tid >> 5, cs = tid & 31;        // 768 rows x 32-way c-split
    int b = row / 384, o = row % 384;
    float qs = (o < 128) ? (kSCALE * kLOG2E) : 1.0f;  // fold softmax exp2 scale into Q
    const float4* wr  = (const float4*)(w_qkv + (size_t)o * 256);
    const float4* sc4 = (const float4*)(fparams + b * 512);
    const float4* sh4 = (const float4*)(fparams + b * 512 + 256);
    unsigned short* arow = Aeff + ((size_t)b * 384 + o) * 256;
    float acc = 0.0f;
#pragma unroll
    for (int j = 0; j < 2; ++j) {
      int c4 = cs * 2 + j;
      float4 wv = wr[c4], scv = sc4[c4], shv = sh4[c4];
      acc += wv.x * shv.x + wv.y * shv.y + wv.z * shv.z + wv.w * shv.w;
      union { unsigned short u[4]; unsigned long long q; } pk;
      pk.u[0] = bf16r(wv.x * scv.x * qs);
      pk.u[1] = bf16r(wv.y * scv.y * qs);
      pk.u[2] = bf16r(wv.z * scv.z * qs);
      pk.u[3] = bf16r(wv.w * scv.w * qs);
      *(unsigned long long*)(arow + c4 * 4) = pk.q;
    }
    acc += __shfl_xor(acc, 1, 64);
    acc += __shfl_xor(acc, 2, 64);
    acc += __shfl_xor(acc, 4, 64);
    acc += __shfl_xor(acc, 8, 64);
    acc += __shfl_xor(acc, 16, 64);
    if (cs == 0) qb[b * 384 + o] = acc * qs;
  } else {
    int t = tid - 24576;   // 512 chunks x 64 elems of w_out (256x128)
    const float4* src = (const float4*)(w_out + (size_t)t * 64);
    unsigned short* dst = WoBf + (size_t)t * 64;
#pragma unroll 4
    for (int i = 0; i < 16; ++i) {
      float4 v = src[i];
      union { unsigned short u[4]; unsigned long long q; } pk;
      pk.u[0] = bf16r(v.x); pk.u[1] = bf16r(v.y);
      pk.u[2] = bf16r(v.z); pk.u[3] = bf16r(v.w);
      *(unsigned long long*)(dst + i * 4) = pk.q;
    }
  }
}

// ---------------------------------------------------------------------------
// qkv_gemm: C[o][p] = Aeff[b] @ xT[b]^T + qb.  M=384,N=4096,K=256 per batch.
// 4-wave block computes 64o x 64p; A/B tiles fully staged into XOR-swizzled
// LDS with coalesced loads (8 full lines per wave-instr).
// V stored TILED: Vt[bh][p>>5][d][p&31] (2KB per 32-key tile).
// ---------------------------------------------------------------------------
__global__ __launch_bounds__(256) void qkv_gemm(const unsigned short* __restrict__ Aeff,
                                                const float* __restrict__ qb,
                                                const unsigned short* __restrict__ xT,
                                                unsigned short* __restrict__ Qb,
                                                unsigned short* __restrict__ Kb,
                                                unsigned short* __restrict__ Vt) {
  __shared__ unsigned short As[64 * 256];   // 32 KB, swizzled
  __shared__ unsigned short Bs[64 * 256];   // 32 KB, swizzled
  int bid = blockIdx.x;               // 768: o_blk fastest (share B tiles in L2)
  int o_blk = bid % 6;
  int rest = bid / 6;                 // 0..127
  int b = rest & 1, p_blk = rest >> 1;
  int t = threadIdx.x;

  const unsigned short* Ag = Aeff + ((size_t)b * 384 + o_blk * 64) * 256;
  const unsigned short* Bg = xT + ((size_t)b * 4096 + p_blk * 64) * 256;

#pragma unroll
  for (int ps = 0; ps < 8; ++ps) {
    int cid = ps * 256 + t;           // 0..2047 16B-chunks
    int row = cid >> 5, ci = cid & 31;
    uint4 va = *(const uint4*)(Ag + row * 256 + ci * 8);
    uint4 vb = *(const uint4*)(Bg + row * 256 + ci * 8);
    int sci = ci ^ (row & 7);         // bank swizzle
    *(uint4*)(As + row * 256 + sci * 8) = va;
    *(uint4*)(Bs + row * 256 + sci * 8) = vb;
  }
  __syncthreads();

  int w = t >> 6, l = t & 63, col = l & 31, hi = l >> 5;
  int wo = w >> 1, wp = w & 1;
  int ao = wo * 32 + col, bp = wp * 32 + col;

  f32x16 acc = zero16();
#pragma unroll
  for (int kc = 0; kc < 256; kc += 16) {
    int ch = (kc >> 3) + hi;
    bf16x8 a0 = ld_frag(As + ao * 256 + (ch ^ (ao & 7)) * 8);
    bf16x8 b0 = ld_frag(Bs + bp * 256 + (ch ^ (bp & 7)) * 8);
    acc = MFMA(a0, b0, acc);
  }

  int obase = o_blk * 64 + wo * 32;        // 32-aligned: one section+head per tile
  int sec = obase >> 7;                    // 0=Q 1=K 2=V
  int head = (obase & 127) >> 5;
  size_t bh = (size_t)b * 4 + head;
  int p = p_blk * 64 + wp * 32 + col;
  if (sec < 2) {
    unsigned short* dst = (sec == 0 ? Qb : Kb) + (bh * 4096 + p) * 32;
#pragma unroll
    for (int g = 0; g < 4; ++g) {
      int dbase = 8 * g + 4 * hi;          // D-row = (reg&3)+8*(reg>>2)+4*hi
      union { unsigned short u[4]; unsigned long long q; } pk;
#pragma unroll
      for (int r = 0; r < 4; ++r)
        pk.u[r] = bf16r(acc[4 * g + r] + qb[b * 384 + obase + dbase + r]);
      *(unsigned long long*)(dst + dbase) = pk.q;
    }
  } else {
    // tiled V: offset = bh*131072 + (p>>5)*1024 + d*32 + (p&31)
    unsigned short* dst = Vt + bh * 131072 + (size_t)(p >> 5) * 1024;
#pragma unroll
    for (int reg = 0; reg < 16; ++reg) {
      int d = (reg & 3) + 8 * (reg >> 2) + 4 * hi;
      dst[d * 32 + (p & 31)] = bf16r(acc[reg] + qb[b * 384 + obase + d]);
    }
  }
}

// ---------------------------------------------------------------------------
// attn: no-max flash attention (range-safe), swapped QK^T.  Block = 4 waves x
// 64q = 256 q rows sharing K/V; keys [ks*512,(ks+1)*512) (16 tiles of 32).
// K/V staged coalesced into chunk-position-major LDS [4][32] 16B tiles
// (conflict-free read banks col*4%32), double-buffered.  Un-normalized
// partials (O, lsum) to ws; attn_merge reduces the 8 K-splits.
// ---------------------------------------------------------------------------
__device__ __forceinline__ void softmax_pv(f32x16 S, bf16x8 va0, bf16x8 va1,
                                           f32x16& O, float& lsum) {
#pragma unroll
  for (int i = 0; i < 16; ++i) S[i] = __builtin_amdgcn_exp2f(S[i]);
  float s0 = (S[0] + S[1]) + (S[2] + S[3]);
  float s1 = (S[4] + S[5]) + (S[6] + S[7]);
  float s2 = (S[8] + S[9]) + (S[10] + S[11]);
  float s3 = (S[12] + S[13]) + (S[14] + S[15]);
  lsum += (s0 + s1) + (s2 + s3);
  // P (D-layout: key=(reg&3)+8*(reg>>2)+4*hi) -> PV B-frags via permlane swaps
  union { __bf16 h[16]; unsigned u[8]; } pu;
#pragma unroll
  for (int i = 0; i < 16; ++i) pu.h[i] = (__bf16)S[i];   // v_cvt_pk_bf16_f32 pairs
  uint2v r0 = PLSWAP(pu.u[0], pu.u[2]);
  uint2v r1 = PLSWAP(pu.u[1], pu.u[3]);
  uint2v r2 = PLSWAP(pu.u[4], pu.u[6]);
  uint2v r3 = PLSWAP(pu.u[5], pu.u[7]);
  union { unsigned u[4]; bf16x8 v; } B0, B1;
  B0.u[0] = r0[0]; B0.u[1] = r1[0]; B0.u[2] = r0[1]; B0.u[3] = r1[1]; // keys 0..15
  B1.u[0] = r2[0]; B1.u[1] = r3[0]; B1.u[2] = r2[1]; B1.u[3] = r3[1]; // keys 16..31
  O = MFMA(va0, B0.v, O);            // O^T[d][q] accumulate
  O = MFMA(va1, B1.v, O);
}

__global__ __launch_bounds__(256, 4) void attn(const unsigned short* __restrict__ Qb,
                                               const unsigned short* __restrict__ Kb,
                                               const unsigned short* __restrict__ Vt,
                                               float* __restrict__ Opart,
                                               float* __restrict__ Lpart) {
  // [buf][K/V][chunk-pos 0..3][row 0..31][8 shorts] = 16 KB
  __shared__ unsigned short kv[2][2][4][32][8];

  int bid = blockIdx.x;               // (bh*8 + ks)*16 + qblk
  int qblk = bid & 15;
  int ks   = (bid >> 4) & 7;
  int bh   = bid >> 7;
  int t = threadIdx.x;
  int w = t >> 6, l = t & 63, col = l & 31, hi = l >> 5;

  int q0 = qblk * 256 + w * 64;
  const unsigned short* Qp = Qb + ((size_t)bh * 4096 + q0) * 32;
  bf16x8 qf0 = ld_frag(Qp + col * 32 + hi * 8);              // q half A: d 0..15
  bf16x8 qf1 = ld_frag(Qp + col * 32 + 16 + hi * 8);         //           d 16..31
  bf16x8 qg0 = ld_frag(Qp + (col + 32) * 32 + hi * 8);       // q half B
  bf16x8 qg1 = ld_frag(Qp + (col + 32) * 32 + 16 + hi * 8);

  // staging role: thread t stages 16B: sec 0=K 1=V, global chunk g, row rr, chunk cc
  int sec = t >> 7, g = t & 127, rr = g >> 2, cc = g & 3;
  const unsigned short* gsrc =
      (sec ? Vt : Kb) + (size_t)bh * 131072 + ks * 16384 + g * 8;

  const f32x16 zc = zero16();
  f32x16 Oa = zero16(), Obb = zero16();
  float lsuma = 0.0f, lsumb = 0.0f;

  uint4 greg = *(const uint4*)(gsrc);            // tile 0

  for (int tt = 0; tt < 16; ++tt) {
    __syncthreads();                             // buf consumers (tt-2) done
    int buf = tt & 1;
    *(uint4*)(&kv[buf][sec][cc][rr][0]) = greg;  // chunk-major, conflict-free
    if (tt < 15) greg = *(const uint4*)(gsrc + (tt + 1) * 1024);  // prefetch
    __syncthreads();                             // tile tt visible

    bf16x8 ka0 = ld_frag(&kv[buf][0][hi][col][0]);
    bf16x8 ka1 = ld_frag(&kv[buf][0][2 + hi][col][0]);
    bf16x8 va0 = ld_frag(&kv[buf][1][hi][col][0]);
    bf16x8 va1 = ld_frag(&kv[buf][1][2 + hi][col][0]);

    f32x16 Sa = MFMA(ka0, qf0, zc);
    Sa = MFMA(ka1, qf1, Sa);
    softmax_pv(Sa, va0, va1, Oa, lsuma);

    f32x16 Sb = MFMA(ka0, qg0, zc);
    Sb = MFMA(ka1, qg1, Sb);
    softmax_pv(Sb, va0, va1, Obb, lsumb);
  }

  uint2v lra = PLSWAP(__float_as_uint(lsuma), __float_as_uint(lsuma));
  uint2v lrb = PLSWAP(__float_as_uint(lsumb), __float_as_uint(lsumb));
  float lta = __uint_as_float(lra[0]) + __uint_as_float(lra[1]);
  float ltb = __uint_as_float(lrb[0]) + __uint_as_float(lrb[1]);

  // ---- write un-normalized partials: Opart[(bh*8+ks)][d][4096q] fp32 ----
  float* op = Opart + (size_t)(bh * 8 + ks) * 131072;
  float* lp = Lpart + (size_t)(bh * 8 + ks) * 4096;
#pragma unroll
  for (int r = 0; r < 16; ++r) {
    int d = (r & 3) + 8 * (r >> 2) + 4 * hi;
    op[d * 4096 + q0 + col]      = Oa[r];
    op[d * 4096 + q0 + 32 + col] = Obb[r];
  }
  if (hi == 0) {
    lp[q0 + col]      = lta;
    lp[q0 + 32 + col] = ltb;
  }
}

// ---------------------------------------------------------------------------
// attn_merge: Ob[bh][q][d] = (sum_ks Opart[bh,ks][d][q]) / (sum_ks Lpart).
// q fastest across threads => all Opart/Lpart reads coalesced.
// ---------------------------------------------------------------------------
__global__ __launch_bounds__(256) void attn_merge(const float* __restrict__ Opart,
                                                  const float* __restrict__ Lpart,
                                                  unsigned short* __restrict__ Ob) {
  int idx = blockIdx.x * 256 + threadIdx.x;   // 524288
  int q  = idx & 4095;
  int rest = idx >> 12;                       // 0..127
  int dp = rest & 15;
  int bh = rest >> 4;
  float s0 = 0.0f, s1 = 0.0f, L = 0.0f;
#pragma unroll
  for (int ks = 0; ks < 8; ++ks) {
    const float* op = Opart + (size_t)(bh * 8 + ks) * 131072;
    s0 += op[(2 * dp) * 4096 + q];
    s1 += op[(2 * dp + 1) * 4096 + q];
    L  += Lpart[(size_t)(bh * 8 + ks) * 4096 + q];
  }
  float inv = 1.0f / L;
  union { unsigned short u[2]; unsigned v; } pk;
  pk.u[0] = bf16r(s0 * inv);
  pk.u[1] = bf16r(s1 * inv);
  *(unsigned*)(Ob + ((size_t)bh * 4096 + q) * 32 + 2 * dp) = pk.v;
}

// ---------------------------------------------------------------------------
// out_gemm: out[b][o][p] = w_out[o][:] @ O[b][:][p] + b_out[o].
// M=256, N=4096, K=128.  4-wave block computes 64o x 64p; A/B staged into
// XOR-swizzled LDS.
// ---------------------------------------------------------------------------
__global__ __launch_bounds__(256) void out_gemm(const unsigned short* __restrict__ Wo,
                                                const unsigned short* __restrict__ Ob,
                                                const float* __restrict__ b_out,
                                                float* __restrict__ out) {
  __shared__ unsigned short As[64 * 128];   // 16 KB
  __shared__ unsigned short Bs[64 * 128];   // 16 KB
  int bid = blockIdx.x;               // 512: o_blk fastest
  int o_blk = bid & 3;
  int rest = bid >> 2;                // 0..127
  int b = rest & 1, p_blk = rest >> 1;
  int t = threadIdx.x;
  int p0 = p_blk * 64;

  const unsigned short* Ag = Wo + (size_t)(o_blk * 64) * 128;
#pragma unroll
  for (int ps = 0; ps < 4; ++ps) {
    int cid = ps * 256 + t;           // 0..1023 16B-chunks
    int row = cid >> 4, ci = cid & 15;
    uint4 va = *(const uint4*)(Ag + row * 128 + ci * 8);
    int head = ci >> 2, dch = ci & 3;
    uint4 vb = *(const uint4*)(Ob + (((size_t)b * 4 + head) * 4096 + p0 + row) * 32 +
                               dch * 8);
    int sci = ci ^ (row & 7);
    *(uint4*)(As + row * 128 + sci * 8) = va;
    *(uint4*)(Bs + row * 128 + sci * 8) = vb;
  }
  __syncthreads();

  int w = t >> 6, l = t & 63, col = l & 31, hi = l >> 5;
  int wo = w >> 1, wp = w & 1;
  int ao = wo * 32 + col, bp = wp * 32 + col;

  f32x16 acc = zero16();
#pragma unroll
  for (int kc = 0; kc < 128; kc += 16) {
    int ch = (kc >> 3) + hi;
    bf16x8 a0 = ld_frag(As + ao * 128 + ((ch ^ (ao & 7)) & 15) * 8);
    bf16x8 b0 = ld_frag(Bs + bp * 128 + ((ch ^ (bp & 7)) & 15) * 8);
    acc = MFMA(a0, b0, acc);
  }
  int p = p0 + wp * 32 + col;
#pragma unroll
  for (int reg = 0; reg < 16; ++reg) {
    int o = o_blk * 64 + wo * 32 + (reg & 3) + 8 * (reg >> 2) + 4 * hi;
    out[((size_t)b * 256 + o) * 4096 + p] = acc[reg] + b_out[o];
  }
}

// ---------------------------------------------------------------------------
extern "C" void kernel_launch(void* const* d_in, const int* in_sizes, int n_in,
                              void* d_out, int out_size, void* d_ws, size_t ws_size,
                              hipStream_t stream) {
  const float* x     = (const float*)d_in[0];
  const float* te    = (const float*)d_in[1];
  const float* w_mlp = (const float*)d_in[2];
  const float* b_mlp = (const float*)d_in[3];
  const float* w_qkv = (const float*)d_in[4];
  const float* w_out = (const float*)d_in[5];
  const float* b_out = (const float*)d_in[6];

  char* ws = (char*)d_ws;
  float*          fparams = (float*)(ws + 0);                 //   4 KB
  float*          qb      = (float*)(ws + 4096);              //   3 KB
  unsigned short* Aeff    = (unsigned short*)(ws + 8192);     // 384 KB
  unsigned short* WoBf    = (unsigned short*)(ws + 401408);   //  64 KB
  unsigned short* xT      = (unsigned short*)(ws + 466944);   //   4 MB
  unsigned short* Qb      = (unsigned short*)(ws + 4661248);  //   2 MB
  unsigned short* Kb      = (unsigned short*)(ws + 6758400);  //   2 MB
  unsigned short* Vt      = (unsigned short*)(ws + 8855552);  //   2 MB
  unsigned short* Ob      = (unsigned short*)(ws + 10952704); //   2 MB
  float*          Opart   = (float*)(ws + 13049856);          //  32 MB
  float*          Lpart   = (float*)(ws + 46604288);          //   1 MB -> 47.7 MB
  float* out = (float*)d_out;

  hipLaunchKernelGGL(prep, dim3(544), dim3(256), 0, stream, x, xT, te, w_mlp,
                     b_mlp, fparams);
  hipLaunchKernelGGL(film2, dim3(98), dim3(256), 0, stream, w_qkv, fparams, w_out,
                     Aeff, qb, WoBf);
  hipLaunchKernelGGL(qkv_gemm, dim3(768), dim3(256), 0, stream, Aeff, qb, xT, Qb, Kb, Vt);
  hipLaunchKernelGGL(attn, dim3(1024), dim3(256), 0, stream, Qb, Kb, Vt, Opart, Lpart);
  hipLaunchKernelGGL(attn_merge, dim3(2048), dim3(256), 0, stream, Opart, Lpart, Ob);
  hipLaunchKernelGGL(out_gemm, dim3(512), dim3(256), 0, stream, WoBf, Ob, b_out, out);
}